// Round 12
// baseline (1486.932 us; speedup 1.0000x reference)
//
#include <hip/hip_runtime.h>

// RNN: h_t = tanh(x_t@Wx^T + b + h_{t-1}@Wh^T), out = all h (fp32).
// Round 12: xp-GEMM FUSED into the scan. Per step each wave computes
// Wx.x(t) (32 MFMAs, x-frags reg-double-buffered, prefetched 1 step ahead)
// + Wh.h(t-1) (32 MFMAs, h-frags polled from the coalesced exchange buffer).
// The Wx work runs under the first poll's in-flight RTT (issue-asm / wait-asm
// split + sched_barrier). Same proven exchange as r10/r11: 16B unit =
// 8 consecutive j x 1 batch, epoch code (1+((t>>1)&1)) in every dword's
// 2 LSBs (tear-detecting), agent-scope ops, lgkm-only barrier, deferred
// out-store. 4 groups x 16 WGs x 4 waves; wave = k-slice 256, 64 j/WG.

typedef unsigned short u16;
typedef unsigned u32;
typedef unsigned long long u64;
typedef __attribute__((ext_vector_type(4))) float f32x4;
typedef __attribute__((ext_vector_type(8))) short bf16x8;
typedef __attribute__((ext_vector_type(4))) u32 u32x4;

__device__ __forceinline__ u16 f2bf(float f) {
  unsigned u = __builtin_bit_cast(unsigned, f);
  unsigned r = (u + 0x7fffu + ((u >> 16) & 1u)) >> 16;  // RTN-even
  return (u16)r;
}

// bf16 with bit0 forced to `bit` (<=1 ULP error: trunc or trunc+1)
__device__ __forceinline__ u16 f2bf_par(float f, unsigned bit) {
  unsigned rt = __builtin_bit_cast(unsigned, f) >> 16;  // truncate
  return (u16)(((rt & 1u) == bit) ? rt : rt + 1u);
}

// tanh via single exp: 1 - 2/(e^{2x}+1)
__device__ __forceinline__ float fast_tanh(float x) {
  float e = __expf(2.0f * x);
  return 1.0f - 2.0f / (e + 1.0f);
}

__device__ __forceinline__ void async_cp16(u16* lds, const u16* g) {
  __builtin_amdgcn_global_load_lds(
      (const __attribute__((address_space(1))) unsigned int*)g,
      (__attribute__((address_space(3))) unsigned int*)lds, 16, 0, 0);
}

// ---------------- conversion kernels ----------------

__global__ __launch_bounds__(256) void conv_x_kernel(const float* __restrict__ in,
                                                     u16* __restrict__ outb) {
  const size_t i = (size_t)blockIdx.x * 256 + threadIdx.x;  // 8-elem chunk id
  const float4* p = (const float4*)(in + (i << 3));
  float4 a = p[0], b = p[1];
  bf16x8 v;
  v[0] = (short)f2bf(a.x); v[1] = (short)f2bf(a.y);
  v[2] = (short)f2bf(a.z); v[3] = (short)f2bf(a.w);
  v[4] = (short)f2bf(b.x); v[5] = (short)f2bf(b.y);
  v[6] = (short)f2bf(b.z); v[7] = (short)f2bf(b.w);
  *(bf16x8*)(outb + (i << 3)) = v;
}

__global__ __launch_bounds__(256) void conv_w_kernel(const float* __restrict__ W,
                                                     u16* __restrict__ Wx,
                                                     u16* __restrict__ Wh) {
  const int i = blockIdx.x * 256 + threadIdx.x;  // 8-elem chunk id, 2048/row
  const int j = i >> 8;          // row 0..1023
  const int c = (i & 255) << 3;  // col 0..2040
  const float4* p = (const float4*)(W + (size_t)j * 2048 + c);
  float4 a = p[0], b = p[1];
  bf16x8 v;
  v[0] = (short)f2bf(a.x); v[1] = (short)f2bf(a.y);
  v[2] = (short)f2bf(a.z); v[3] = (short)f2bf(a.w);
  v[4] = (short)f2bf(b.x); v[5] = (short)f2bf(b.y);
  v[6] = (short)f2bf(b.z); v[7] = (short)f2bf(b.w);
  u16* dst = (c < 1024) ? (Wx + (size_t)j * 1024 + c)
                        : (Wh + (size_t)j * 1024 + (c - 1024));
  *(bf16x8*)dst = v;
}

// ---------------- fused recurrent scan ----------------
// H buffer: 2 x [g4][joct128][batch16][16B]; joct = j>>3. Consumer wave wv
// (k-slice [256wv,+256)): 8 x dwordx4, kk-stride 1024B, two 4096B bases.
// Producer lane: jq = 16wloc+4wv+lhi; 8B pack at ((jq>>1)<<8)+(l16<<4)+((jq&1)<<3).

#define CHECK8(OKVAR)                                                       \
  {                                                                         \
    OKVAR = 1u;                                                             \
    _Pragma("unroll") for (int d = 0; d < 4; ++d) {                         \
      OKVAR &= (u32)(((f0[d] & 1u) | (((f0[d] >> 16) & 1u) << 1)) == e);    \
      OKVAR &= (u32)(((f1[d] & 1u) | (((f1[d] >> 16) & 1u) << 1)) == e);    \
      OKVAR &= (u32)(((f2[d] & 1u) | (((f2[d] >> 16) & 1u) << 1)) == e);    \
      OKVAR &= (u32)(((f3[d] & 1u) | (((f3[d] >> 16) & 1u) << 1)) == e);    \
      OKVAR &= (u32)(((f4[d] & 1u) | (((f4[d] >> 16) & 1u) << 1)) == e);    \
      OKVAR &= (u32)(((f5[d] & 1u) | (((f5[d] >> 16) & 1u) << 1)) == e);    \
      OKVAR &= (u32)(((f6[d] & 1u) | (((f6[d] >> 16) & 1u) << 1)) == e);    \
      OKVAR &= (u32)(((f7[d] & 1u) | (((f7[d] >> 16) & 1u) << 1)) == e);    \
    }                                                                       \
  }

__global__ __launch_bounds__(256) void rnn_scan(float* __restrict__ out,
                                                const u16* __restrict__ Wh,
                                                const u16* __restrict__ Wx,
                                                const u16* __restrict__ xb,
                                                const float* __restrict__ bias,
                                                char* __restrict__ Hb) {
  const int wg = blockIdx.x;   // 0..63
  const int g = wg & 3;        // group (16 batches)
  const int wloc = wg >> 2;    // 0..15 (64-j slice)
  const int tid = threadIdx.x;
  const int lane = tid & 63;
  const int wv = tid >> 6;     // 0..3 (k-slice AND j-tile owner)
  const int l16 = lane & 15;
  const int lhi = lane >> 4;

  __shared__ __align__(16) f32x4 red[2][4][4][64];  // 32KB dbuf

  // Weight frags: af = Wh, afx = Wx; [jt][kk] = W[64wloc+16jt+l16][256wv+32kk+8lhi..+8]
  bf16x8 af[4][8], afx[4][8];
  {
    const size_t roff = (size_t)((wloc << 6) + l16) * 1024 + (wv << 8) + (lhi << 3);
    const u16* wp = Wh + roff;
    const u16* wpx = Wx + roff;
#pragma unroll
    for (int jt = 0; jt < 4; ++jt)
#pragma unroll
      for (int kk = 0; kk < 8; ++kk) {
        af[jt][kk] = *(const bf16x8*)(wp + (jt << 14) + (kk << 5));
        afx[jt][kk] = *(const bf16x8*)(wpx + (jt << 14) + (kk << 5));
      }
  }

  const int b = (g << 4) + l16;
  const int hread = (g << 15) + (((wv << 5) + lhi) << 8) + (l16 << 4);
  const int jq = (wloc << 4) + (wv << 2) + lhi;
  const int hwrite = (g << 15) + ((jq >> 1) << 8) + (l16 << 4) + ((jq & 1) << 3);
  const int j0 = jq << 2;
  float* pout = out + ((size_t)b << 19) + j0;        // b*512*1024 + j
  const u16* xbase = xb + ((size_t)b << 19) + (wv << 8) + (lhi << 3);
  const f32x4 bv = *(const f32x4*)(bias + j0);

  // x-fragment double buffer (static indices only -> registers)
  u32x4 xfCur[8], xfNext[8];
#pragma unroll
  for (int kk = 0; kk < 8; ++kk)
    xfNext[kk] = *(const u32x4*)(xbase + (kk << 5));  // t=0

  f32x4 hvP = {0.f, 0.f, 0.f, 0.f};

#pragma unroll 1
  for (int t = 0; t < 512; ++t) {
    // rotate x-frags (compiler inserts exact counted vmcnt for aged loads)
#pragma unroll
    for (int kk = 0; kk < 8; ++kk) xfCur[kk] = xfNext[kk];

    f32x4 acc[4] = {};
    const char* Hs = Hb + (((t - 1) & 1) << 17) + hread;
    const char* Hs2 = Hs + 4096;
    u32x4 f0, f1, f2, f3, f4, f5, f6, f7;

    if (t > 0) {
      // issue first poll attempt WITHOUT waiting -> Wx MFMAs run under RTT
      asm volatile(
          "global_load_dwordx4 %0, %8, off sc0 sc1\n\t"
          "global_load_dwordx4 %1, %8, off offset:1024 sc0 sc1\n\t"
          "global_load_dwordx4 %2, %8, off offset:2048 sc0 sc1\n\t"
          "global_load_dwordx4 %3, %8, off offset:3072 sc0 sc1\n\t"
          "global_load_dwordx4 %4, %9, off sc0 sc1\n\t"
          "global_load_dwordx4 %5, %9, off offset:1024 sc0 sc1\n\t"
          "global_load_dwordx4 %6, %9, off offset:2048 sc0 sc1\n\t"
          "global_load_dwordx4 %7, %9, off offset:3072 sc0 sc1"
          : "=&v"(f0), "=&v"(f1), "=&v"(f2), "=&v"(f3), "=&v"(f4),
            "=&v"(f5), "=&v"(f6), "=&v"(f7)
          : "v"(Hs), "v"(Hs2)
          : "memory");
    }

    // Wx . x(t) — no global dependency, hides under the poll RTT
    {
      union { u32x4 u; bf16x8 v; } xu;
#pragma unroll
      for (int kk = 0; kk < 8; ++kk) {
        xu.u = xfCur[kk];
#pragma unroll
        for (int jt = 0; jt < 4; ++jt)
          acc[jt] = __builtin_amdgcn_mfma_f32_16x16x32_bf16(afx[jt][kk], xu.v,
                                                            acc[jt], 0, 0, 0);
      }
    }

    if (t > 0) {
      const u32 e = 1u + ((((u32)t - 1u) >> 1) & 1u);
      asm volatile("s_waitcnt vmcnt(0)" ::: "memory");
      __builtin_amdgcn_sched_barrier(0);  // rule #18: pin the check after wait
      u32 ok;
      CHECK8(ok)
      while (!__all((int)ok)) {
        asm volatile(
            "global_load_dwordx4 %0, %8, off sc0 sc1\n\t"
            "global_load_dwordx4 %1, %8, off offset:1024 sc0 sc1\n\t"
            "global_load_dwordx4 %2, %8, off offset:2048 sc0 sc1\n\t"
            "global_load_dwordx4 %3, %8, off offset:3072 sc0 sc1\n\t"
            "global_load_dwordx4 %4, %9, off sc0 sc1\n\t"
            "global_load_dwordx4 %5, %9, off offset:1024 sc0 sc1\n\t"
            "global_load_dwordx4 %6, %9, off offset:2048 sc0 sc1\n\t"
            "global_load_dwordx4 %7, %9, off offset:3072 sc0 sc1\n\t"
            "s_waitcnt vmcnt(0)"
            : "=&v"(f0), "=&v"(f1), "=&v"(f2), "=&v"(f3), "=&v"(f4),
              "=&v"(f5), "=&v"(f6), "=&v"(f7)
            : "v"(Hs), "v"(Hs2)
            : "memory");
        __builtin_amdgcn_sched_barrier(0);
        CHECK8(ok)
      }
      // deferred out-store of h(t-1): ages a full step before next poll
      __builtin_nontemporal_store(hvP,
                                  (f32x4*)(pout + ((size_t)(t - 1) << 10)));
      // Wh . h(t-1)
      union { u32x4 u; bf16x8 v; } c[8];
      c[0].u = f0; c[1].u = f1; c[2].u = f2; c[3].u = f3;
      c[4].u = f4; c[5].u = f5; c[6].u = f6; c[7].u = f7;
#pragma unroll
      for (int kk = 0; kk < 8; ++kk)
#pragma unroll
        for (int jt = 0; jt < 4; ++jt)
          acc[jt] = __builtin_amdgcn_mfma_f32_16x16x32_bf16(af[jt][kk], c[kk].v,
                                                            acc[jt], 0, 0, 0);
    }

    // prefetch x-frags for t+1 (clamped; OOB-free)
    {
      const u16* xnp = xbase + ((size_t)((t < 511) ? t + 1 : 511) << 10);
#pragma unroll
      for (int kk = 0; kk < 8; ++kk)
        xfNext[kk] = *(const u32x4*)(xnp + (kk << 5));
    }

    const int rb = t & 1;
#pragma unroll
    for (int jt = 0; jt < 4; ++jt) red[rb][wv][jt][lane] = acc[jt];
    // lgkm-only barrier: do NOT drain vmcnt (publish/out/xf stay in flight)
    asm volatile("s_waitcnt lgkmcnt(0)\n\ts_barrier" ::: "memory");

    f32x4 s = red[rb][0][wv][lane];
#pragma unroll
    for (int w = 1; w < 4; ++w) s += red[rb][w][wv][lane];

    const float h0 = fast_tanh(s[0] + bv[0]);
    const float h1 = fast_tanh(s[1] + bv[1]);
    const float h2 = fast_tanh(s[2] + bv[2]);
    const float h3 = fast_tanh(s[3] + bv[3]);

    // publish: epoch code in the 2 LSBs of every dword (tear-detecting)
    const u32 code = 1u + (((u32)t >> 1) & 1u);
    const u32 c0b = code & 1u, c1b = (code >> 1) & 1u;
    const u64 pack = (u64)f2bf_par(h0, c0b) | ((u64)f2bf_par(h1, c1b) << 16) |
                     ((u64)f2bf_par(h2, c0b) << 32) |
                     ((u64)f2bf_par(h3, c1b) << 48);
    __hip_atomic_store((u64*)(Hb + ((t & 1) << 17) + hwrite), pack,
                       __ATOMIC_RELAXED, __HIP_MEMORY_SCOPE_AGENT);

    hvP[0] = h0; hvP[1] = h1; hvP[2] = h2; hvP[3] = h3;
  }
  __builtin_nontemporal_store(hvP, (f32x4*)(pout + ((size_t)511 << 10)));
}

// ---------------- launcher ----------------

extern "C" void kernel_launch(void* const* d_in, const int* in_sizes, int n_in,
                              void* d_out, int out_size, void* d_ws,
                              size_t ws_size, hipStream_t stream) {
  const float* x = (const float*)d_in[0];     // [64][512][1024]
  const float* W = (const float*)d_in[1];     // [1024][2048]
  const float* bias = (const float*)d_in[2];  // [1024]
  float* out = (float*)d_out;                 // [64][512][1024]

  char* ws = (char*)d_ws;
  u16* xb = (u16*)ws;                           // 67,108,864 B
  u16* Wxb = (u16*)(ws + 67108864);             //  2,097,152 B
  u16* Whb = (u16*)(ws + 69206016);             //  2,097,152 B
  char* Hbuf = (char*)(ws + 71303168);          //    262,144 B (2 x 128KB)

  (void)hipMemsetAsync(Hbuf, 0, 262144, stream);  // all dword codes -> 0
  conv_x_kernel<<<16384, 256, 0, stream>>>(x, xb);
  conv_w_kernel<<<1024, 256, 0, stream>>>(W, Wxb, Whb);
  rnn_scan<<<64, 256, 0, stream>>>(out, Whb, Wxb, xb, bias, Hbuf);
}

// Round 13
// 1114.921 us; speedup vs baseline: 1.3337x; 1.3337x over previous
//
#include <hip/hip_runtime.h>

// RNN: h_t = tanh(x_t@Wx^T + b + h_{t-1}@Wh^T), out = all h (fp32).
// Round 13: r11 scan (proven 947us) + xp-GEMM merged into the SAME kernel
// as extra blocks (64 scan WGs + 2048 GEMM WGs). GEMM tiles are t-major
// ordered and publish per-t-quarter watermarks (sc0sc1 stores + vmcnt(0) +
// relaxed agent atomicAdd - the r2/r3-proven visibility pattern). The scan
// guards its distance-2 xp prefetch on the watermark (3 checks total after
// ramp) and reads xp via sc0sc1. conv_x is folded into GEMM A-staging
// (fp32 -> bf16 inline). h exchange: r10/r11 coalesced layout, epoch code
// in every dword's 2 LSBs, agent-scope ops, lgkm-only barrier, deferred
// out-store, distance-2 xp parity prefetch.

typedef unsigned short u16;
typedef unsigned u32;
typedef unsigned long long u64;
typedef __attribute__((ext_vector_type(4))) float f32x4;
typedef __attribute__((ext_vector_type(8))) short bf16x8;
typedef __attribute__((ext_vector_type(4))) u32 u32x4;

__device__ __forceinline__ u16 f2bf(float f) {
  unsigned u = __builtin_bit_cast(unsigned, f);
  unsigned r = (u + 0x7fffu + ((u >> 16) & 1u)) >> 16;  // RTN-even
  return (u16)r;
}

// bf16 with bit0 forced to `bit` (<=1 ULP error: trunc or trunc+1)
__device__ __forceinline__ u16 f2bf_par(float f, unsigned bit) {
  unsigned rt = __builtin_bit_cast(unsigned, f) >> 16;  // truncate
  return (u16)(((rt & 1u) == bit) ? rt : rt + 1u);
}

// tanh via single exp: 1 - 2/(e^{2x}+1)
__device__ __forceinline__ float fast_tanh(float x) {
  float e = __expf(2.0f * x);
  return 1.0f - 2.0f / (e + 1.0f);
}

__device__ __forceinline__ void async_cp16(u16* lds, const u16* g) {
  __builtin_amdgcn_global_load_lds(
      (const __attribute__((address_space(1))) unsigned int*)g,
      (__attribute__((address_space(3))) unsigned int*)lds, 16, 0, 0);
}

// sc0sc1 (MALL-coherent) helpers
__device__ __forceinline__ f32x4 ld_xp16(const float* p) {
  f32x4 v;
  asm volatile("global_load_dwordx4 %0, %1, off sc0 sc1\n\ts_waitcnt vmcnt(0)"
               : "=v"(v) : "v"(p) : "memory");
  return v;
}
__device__ __forceinline__ void st_f32(float* p, float v) {
  asm volatile("global_store_dword %0, %1, off sc0 sc1" ::"v"(p), "v"(v)
               : "memory");
}

// ---------------- conv_w ----------------

__global__ __launch_bounds__(256) void conv_w_kernel(const float* __restrict__ W,
                                                     u16* __restrict__ Wx,
                                                     u16* __restrict__ Wh) {
  const int i = blockIdx.x * 256 + threadIdx.x;  // 8-elem chunk id, 2048/row
  const int j = i >> 8;          // row 0..1023
  const int c = (i & 255) << 3;  // col 0..2040
  const float4* p = (const float4*)(W + (size_t)j * 2048 + c);
  float4 a = p[0], b = p[1];
  bf16x8 v;
  v[0] = (short)f2bf(a.x); v[1] = (short)f2bf(a.y);
  v[2] = (short)f2bf(a.z); v[3] = (short)f2bf(a.w);
  v[4] = (short)f2bf(b.x); v[5] = (short)f2bf(b.y);
  v[6] = (short)f2bf(b.z); v[7] = (short)f2bf(b.w);
  u16* dst = (c < 1024) ? (Wx + (size_t)j * 1024 + c)
                        : (Wh + (size_t)j * 1024 + (c - 1024));
  *(bf16x8*)dst = v;
}

// ---------------- merged kernel: scan (blocks 0-63) + GEMM (64-2111) ----

__global__ __launch_bounds__(256) void rnn_fused(float* __restrict__ out,
                                                 const u16* __restrict__ Wh,
                                                 const u16* __restrict__ Wx,
                                                 const float* __restrict__ x,
                                                 const float* __restrict__ bias,
                                                 char* __restrict__ Hb,
                                                 u32* __restrict__ wm) {
  __shared__ __align__(16) f32x4 red[2][4][4][64];  // 32KB (scan)
  __shared__ __align__(16) u16 Alds[128 * 32];      // 8KB  (gemm)
  __shared__ __align__(16) u16 Blds[128 * 32];      // 8KB  (gemm)

  const int bid = blockIdx.x;
  const int tid = threadIdx.x;
  const int lane = tid & 63;
  const int wv = tid >> 6;
  const int l16 = lane & 15;
  const int lhi = lane >> 4;

  if (bid >= 64) {
    // ---------------- GEMM part: xp = x@Wx^T + b -> out (sc0sc1) ----------
    const int q = bid - 64;      // 0..2047
    const int d = q >> 3;        // m-tile, t-major order
    const int nq = q & 7;
    const int bq = d & 63;
    const int tq = d >> 6;       // 0..3 (t-quarter)
    const int m0 = (bq << 9) + (tq << 7);
    const int n0 = nq << 7;
    const int mw = (wv >> 1) << 6;
    const int nw = (wv & 1) << 6;

    f32x4 acc[4][4] = {};

    for (int kt = 0; kt < 32; ++kt) {
      const int k0 = kt << 5;
#pragma unroll
      for (int i = 0; i < 2; ++i) {
        const int off = (i << 11) + (tid << 3);
        const int row = off >> 5;
        const int col = off & 31;
        // A: x fp32 -> bf16 inline (replaces conv_x)
        const float* ap = x + (size_t)(m0 + row) * 1024 + k0 + col;
        float4 a0 = *(const float4*)ap;
        float4 a1 = *(const float4*)(ap + 4);
        bf16x8 av;
        av[0] = (short)f2bf(a0.x); av[1] = (short)f2bf(a0.y);
        av[2] = (short)f2bf(a0.z); av[3] = (short)f2bf(a0.w);
        av[4] = (short)f2bf(a1.x); av[5] = (short)f2bf(a1.y);
        av[6] = (short)f2bf(a1.z); av[7] = (short)f2bf(a1.w);
        *(bf16x8*)&Alds[off] = av;
        async_cp16(&Blds[off], Wx + (size_t)(n0 + row) * 1024 + k0 + col);
      }
      __syncthreads();  // drains vmcnt + lgkm -> LDS ready
      bf16x8 af[4], bf[4];
#pragma unroll
      for (int mi = 0; mi < 4; ++mi)
        af[mi] = *(const bf16x8*)&Alds[((mw + (mi << 4) + l16) << 5) +
                                       (lhi << 3)];
#pragma unroll
      for (int ni = 0; ni < 4; ++ni)
        bf[ni] = *(const bf16x8*)&Blds[((nw + (ni << 4) + l16) << 5) +
                                       (lhi << 3)];
#pragma unroll
      for (int mi = 0; mi < 4; ++mi)
#pragma unroll
        for (int ni = 0; ni < 4; ++ni)
          acc[mi][ni] = __builtin_amdgcn_mfma_f32_16x16x32_bf16(
              af[mi], bf[ni], acc[mi][ni], 0, 0, 0);
      __syncthreads();
    }

    float bv[4];
#pragma unroll
    for (int ni = 0; ni < 4; ++ni) bv[ni] = bias[n0 + nw + (ni << 4) + l16];
#pragma unroll
    for (int mi = 0; mi < 4; ++mi) {
#pragma unroll
      for (int r = 0; r < 4; ++r) {
        const int row = m0 + mw + (mi << 4) + (lhi << 2) + r;
        float* cp = out + (size_t)row * 1024 + n0 + nw + l16;
#pragma unroll
        for (int ni = 0; ni < 4; ++ni)
          st_f32(cp + (ni << 4), acc[mi][ni][r] + bv[ni]);
      }
    }
    asm volatile("s_waitcnt vmcnt(0)" ::: "memory");  // stores acked at MALL
    __syncthreads();
    if (tid == 0)
      __hip_atomic_fetch_add(wm + tq, 1u, __ATOMIC_RELAXED,
                             __HIP_MEMORY_SCOPE_AGENT);
    return;
  }

  // ---------------- scan part (r11 verbatim + watermark-guarded xp) ------
  const int g = bid & 3;       // group (16 batches)
  const int wloc = bid >> 2;   // 0..15 (64-j slice)

  // A-frags: af[jt][kk] = Wh[64wloc+16jt+l16][256wv + 32kk + 8lhi .. +8]
  bf16x8 af[4][8];
  {
    const u16* wp =
        Wh + (size_t)((wloc << 6) + l16) * 1024 + (wv << 8) + (lhi << 3);
#pragma unroll
    for (int jt = 0; jt < 4; ++jt)
#pragma unroll
      for (int kk = 0; kk < 8; ++kk)
        af[jt][kk] = *(const bf16x8*)(wp + (jt << 14) + (kk << 5));
  }

  const int b = (g << 4) + l16;
  const int hread = (g << 15) + (((wv << 5) + lhi) << 8) + (l16 << 4);
  const int jq = (wloc << 4) + (wv << 2) + lhi;
  const int hwrite = (g << 15) + ((jq >> 1) << 8) + (l16 << 4) + ((jq & 1) << 3);
  const int j0 = jq << 2;
  float* pout = out + ((size_t)b << 19) + j0;  // b*512*1024 + j

  // wait for xp t in [0,128) then load t=0,1
  {
    u32 w;
    do {
      w = __hip_atomic_load(wm, __ATOMIC_RELAXED, __HIP_MEMORY_SCOPE_AGENT);
    } while (w != 512u);
  }
  f32x4 xpA = ld_xp16(pout);           // t=0
  f32x4 xpB = ld_xp16(pout + 1024);    // t=1
  f32x4 hvP = {0.f, 0.f, 0.f, 0.f};
  int ready_tq = 0;

#pragma unroll 1
  for (int t = 0; t < 512; ++t) {
    f32x4 acc[4] = {};
    if (t > 0) {
      const u32 e = 1u + ((((u32)t - 1u) >> 1) & 1u);
      const char* Hs = Hb + (((t - 1) & 1) << 17) + hread;
      const char* Hs2 = Hs + 4096;
      u32x4 f0, f1, f2, f3, f4, f5, f6, f7;
      while (true) {
        asm volatile(
            "global_load_dwordx4 %0, %8, off sc0 sc1\n\t"
            "global_load_dwordx4 %1, %8, off offset:1024 sc0 sc1\n\t"
            "global_load_dwordx4 %2, %8, off offset:2048 sc0 sc1\n\t"
            "global_load_dwordx4 %3, %8, off offset:3072 sc0 sc1\n\t"
            "global_load_dwordx4 %4, %9, off sc0 sc1\n\t"
            "global_load_dwordx4 %5, %9, off offset:1024 sc0 sc1\n\t"
            "global_load_dwordx4 %6, %9, off offset:2048 sc0 sc1\n\t"
            "global_load_dwordx4 %7, %9, off offset:3072 sc0 sc1\n\t"
            "s_waitcnt vmcnt(0)"
            : "=&v"(f0), "=&v"(f1), "=&v"(f2), "=&v"(f3), "=&v"(f4),
              "=&v"(f5), "=&v"(f6), "=&v"(f7)
            : "v"(Hs), "v"(Hs2)
            : "memory");
        u32 ok = 1u;
#pragma unroll
        for (int dd = 0; dd < 4; ++dd) {
          ok &= (u32)(((f0[dd] & 1u) | (((f0[dd] >> 16) & 1u) << 1)) == e);
          ok &= (u32)(((f1[dd] & 1u) | (((f1[dd] >> 16) & 1u) << 1)) == e);
          ok &= (u32)(((f2[dd] & 1u) | (((f2[dd] >> 16) & 1u) << 1)) == e);
          ok &= (u32)(((f3[dd] & 1u) | (((f3[dd] >> 16) & 1u) << 1)) == e);
          ok &= (u32)(((f4[dd] & 1u) | (((f4[dd] >> 16) & 1u) << 1)) == e);
          ok &= (u32)(((f5[dd] & 1u) | (((f5[dd] >> 16) & 1u) << 1)) == e);
          ok &= (u32)(((f6[dd] & 1u) | (((f6[dd] >> 16) & 1u) << 1)) == e);
          ok &= (u32)(((f7[dd] & 1u) | (((f7[dd] >> 16) & 1u) << 1)) == e);
        }
        if (__all((int)ok)) break;
      }
      // deferred out-store of h(t-1): ages a full step before next poll
      __builtin_nontemporal_store(hvP,
                                  (f32x4*)(pout + ((size_t)(t - 1) << 10)));
      union { u32x4 u; bf16x8 v; } c[8];
      c[0].u = f0; c[1].u = f1; c[2].u = f2; c[3].u = f3;
      c[4].u = f4; c[5].u = f5; c[6].u = f6; c[7].u = f7;
#pragma unroll
      for (int kk = 0; kk < 8; ++kk)
#pragma unroll
        for (int jt = 0; jt < 4; ++jt)
          acc[jt] = __builtin_amdgcn_mfma_f32_16x16x32_bf16(af[jt][kk], c[kk].v,
                                                            acc[jt], 0, 0, 0);
    }

    const int rb = t & 1;
#pragma unroll
    for (int jt = 0; jt < 4; ++jt) red[rb][wv][jt][lane] = acc[jt];
    // lgkm-only barrier: do NOT drain vmcnt (publish/out stay in flight)
    asm volatile("s_waitcnt lgkmcnt(0)\n\ts_barrier" ::: "memory");

    f32x4 s = red[rb][0][wv][lane];
#pragma unroll
    for (int w = 1; w < 4; ++w) s += red[rb][w][wv][lane];

    const f32x4 xp = (t & 1) ? xpB : xpA;
    const float h0 = fast_tanh(xp[0] + s[0]);
    const float h1 = fast_tanh(xp[1] + s[1]);
    const float h2 = fast_tanh(xp[2] + s[2]);
    const float h3 = fast_tanh(xp[3] + s[3]);

    // publish: epoch code in the 2 LSBs of every dword (tear-detecting)
    const u32 code = 1u + (((u32)t >> 1) & 1u);
    const u32 c0b = code & 1u, c1b = (code >> 1) & 1u;
    const u64 pack = (u64)f2bf_par(h0, c0b) | ((u64)f2bf_par(h1, c1b) << 16) |
                     ((u64)f2bf_par(h2, c0b) << 32) |
                     ((u64)f2bf_par(h3, c1b) << 48);
    __hip_atomic_store((u64*)(Hb + ((t & 1) << 17) + hwrite), pack,
                       __ATOMIC_RELAXED, __HIP_MEMORY_SCOPE_AGENT);

    // xp prefetch, distance 2, watermark-guarded, into the parity register
    if (t + 2 < 512) {
      const int tq2 = (t + 2) >> 7;
      if (tq2 > ready_tq) {
        u32 w;
        do {
          w = __hip_atomic_load(wm + tq2, __ATOMIC_RELAXED,
                                __HIP_MEMORY_SCOPE_AGENT);
        } while (w != 512u);
        ready_tq = tq2;
      }
      const f32x4 v = ld_xp16(pout + ((size_t)(t + 2) << 10));
      if (t & 1)
        xpB = v;
      else
        xpA = v;
    }
    hvP[0] = h0; hvP[1] = h1; hvP[2] = h2; hvP[3] = h3;
  }
  __builtin_nontemporal_store(hvP, (f32x4*)(pout + ((size_t)511 << 10)));
}

// ---------------- launcher ----------------

extern "C" void kernel_launch(void* const* d_in, const int* in_sizes, int n_in,
                              void* d_out, int out_size, void* d_ws,
                              size_t ws_size, hipStream_t stream) {
  const float* x = (const float*)d_in[0];     // [64][512][1024]
  const float* W = (const float*)d_in[1];     // [1024][2048]
  const float* bias = (const float*)d_in[2];  // [1024]
  float* out = (float*)d_out;                 // [64][512][1024]

  char* ws = (char*)d_ws;
  u16* Wxb = (u16*)ws;                          // 2,097,152 B
  u16* Whb = (u16*)(ws + 2097152);              // 2,097,152 B
  char* Hbuf = (char*)(ws + 4194304);           //   262,144 B (2 x 128KB)
  u32* wm = (u32*)(ws + 4456448);               //        64 B

  (void)hipMemsetAsync(Hbuf, 0, 262144 + 64, stream);  // H stale + wm = 0
  conv_w_kernel<<<1024, 256, 0, stream>>>(W, Wxb, Whb);
  rnn_fused<<<2112, 256, 0, stream>>>(out, Whb, Wxb, x, bias, Hbuf, wm);
}